// Round 1
// baseline (1420.998 us; speedup 1.0000x reference)
//
#include <hip/hip_runtime.h>
#include <stdint.h>

#define OUTF 11008
#define INF  4096
#define NG   32      // groups = INF/128
#define TOK  8192
#define KB4  2048    // int32 (bytes) per qweight row = INF/2

#define BM 128
#define BN 128
#define BK 64

typedef unsigned short u16;
typedef __attribute__((ext_vector_type(8))) short bf16x8;
typedef __attribute__((ext_vector_type(4))) float f32x4;

// fp32 -> bf16 round-to-nearest-even (inputs finite)
__device__ inline u16 f2bf(float f) {
  union { float f; uint32_t u; } v; v.f = f;
  return (u16)((v.u + 0x7fff + ((v.u >> 16) & 1)) >> 16);
}

// async global->LDS, 16B per lane; lds dest must be wave-uniform base (+lane*16 implicit)
__device__ inline void async_copy16(const void* g, const void* l) {
  __builtin_amdgcn_global_load_lds(
      (__attribute__((address_space(1))) void*)(g),
      (__attribute__((address_space(3))) void*)(l), 16, 0, 0);
}

// ---------------- preprocessing kernels ----------------

__global__ void dequant_w(const int* __restrict__ QW, const float* __restrict__ scales,
                          const float* __restrict__ zeros, u16* __restrict__ Wb) {
  const int idx = blockIdx.x * 256 + threadIdx.x;   // one per 4 packed bytes
  const int e = idx * 4;
  const int o = e >> 11;            // /KB4
  const int c = e & (KB4 - 1);
  const int g = c >> 6;             // group of weight cols 2c..2c+7 (c%4==0, safe)
  const float s = scales[o * NG + g];
  const float z = zeros[o * NG + g];
  const float zs = -z * s;
  const int4 q = *(const int4*)(QW + (size_t)o * KB4 + c);
  const int qq[4] = {q.x, q.y, q.z, q.w};
  union { u16 t[8]; int4 v; } u;
#pragma unroll
  for (int j = 0; j < 4; ++j) {
    u.t[2 * j]     = f2bf(fmaf((float)(qq[j] & 15), s, zs));
    u.t[2 * j + 1] = f2bf(fmaf((float)((qq[j] >> 4) & 15), s, zs));
  }
  *(int4*)(Wb + (size_t)o * INF + 2 * c) = u.v;
}

__global__ void cvt_x(const float* __restrict__ X, u16* __restrict__ Xb) {
  const size_t base = ((size_t)blockIdx.x * 256 + threadIdx.x) * 8;
  const float4 a = *(const float4*)(X + base);
  const float4 b = *(const float4*)(X + base + 4);
  union { u16 t[8]; int4 v; } u;
  u.t[0] = f2bf(a.x); u.t[1] = f2bf(a.y); u.t[2] = f2bf(a.z); u.t[3] = f2bf(a.w);
  u.t[4] = f2bf(b.x); u.t[5] = f2bf(b.y); u.t[6] = f2bf(b.z); u.t[7] = f2bf(b.w);
  *(int4*)(Xb + base) = u.v;
}

// ---------------- shared GEMM compute/epilogue ----------------
// A-frag: A[m=lane&15][k=(lane>>4)*8+j]; B-frag symmetric (B^T input).
// C/D: col=lane&15, row=(lane>>4)*4+reg.

#define MFMA_COMPUTE()                                                        \
  do {                                                                        \
    _Pragma("unroll") for (int ks = 0; ks < 2; ++ks) {                        \
      bf16x8 af[4], bfr[4];                                                   \
      const int kk = ks * 32 + (lane >> 4) * 8;                               \
      const int rr = lane & 15;                                               \
      _Pragma("unroll") for (int i = 0; i < 4; ++i) {                         \
        af[i]  = *(const bf16x8*)&As[(mwave + i * 16 + rr) * BK + kk];        \
        bfr[i] = *(const bf16x8*)&Bs[(nwave + i * 16 + rr) * BK + kk];        \
      }                                                                       \
      _Pragma("unroll") for (int mi = 0; mi < 4; ++mi)                        \
        _Pragma("unroll") for (int ni = 0; ni < 4; ++ni)                      \
          acc[mi][ni] = __builtin_amdgcn_mfma_f32_16x16x32_bf16(              \
              af[mi], bfr[ni], acc[mi][ni], 0, 0, 0);                         \
    }                                                                         \
  } while (0)

#define EPILOGUE()                                                            \
  do {                                                                        \
    const int ncol = lane & 15;                                               \
    const int qrow = (lane >> 4) * 4;                                         \
    _Pragma("unroll") for (int mi = 0; mi < 4; ++mi)                          \
      _Pragma("unroll") for (int ni = 0; ni < 4; ++ni) {                      \
        const int gn = bn * BN + nwave + ni * 16 + ncol;                      \
        const float bv = bias[gn];                                            \
        _Pragma("unroll") for (int r = 0; r < 4; ++r) {                       \
          const int gm = bm * BM + mwave + mi * 16 + qrow + r;                \
          C[(size_t)gm * OUTF + gn] = acc[mi][ni][r] + bv;                    \
        }                                                                     \
      }                                                                       \
  } while (0)

// ---------------- main GEMM (preprocessed bf16 A,B in ws) ----------------

__global__ __launch_bounds__(256) void gemm_pre(const u16* __restrict__ A,
                                                const u16* __restrict__ B,
                                                const float* __restrict__ bias,
                                                float* __restrict__ C) {
  __shared__ __align__(16) u16 As[BM * BK];   // 16 KB, unpadded (global_load_lds)
  __shared__ __align__(16) u16 Bs[BN * BK];   // 16 KB
  const int tid = threadIdx.x;
  const int lane = tid & 63;
  const int wid = __builtin_amdgcn_readfirstlane(tid >> 6);
  const int bm = blockIdx.y, bn = blockIdx.x;
  const u16* Ab = A + (size_t)bm * BM * INF;
  const u16* Bb = B + (size_t)bn * BN * INF;
  const int sr = lane >> 3;        // row within 8-row group
  const int sc = (lane & 7) * 8;   // 16B chunk within 64-wide k slab
  const int mwave = (wid >> 1) * 64;
  const int nwave = (wid & 1) * 64;
  f32x4 acc[4][4] = {};

  for (int kb = 0; kb < INF / BK; ++kb) {
    const int k0 = kb * BK;
#pragma unroll
    for (int j = 0; j < 4; ++j) {
      const int rg = wid * 4 + j;          // 8-row group index, wave-uniform
      const int row = rg * 8 + sr;
      async_copy16(Ab + (size_t)row * INF + k0 + sc, (const char*)As + rg * 1024);
      async_copy16(Bb + (size_t)row * INF + k0 + sc, (const char*)Bs + rg * 1024);
    }
    __syncthreads();
    MFMA_COMPUTE();
    __syncthreads();
  }
  EPILOGUE();
}

// ---------------- fused fallback (no workspace requirement) ----------------

__global__ __launch_bounds__(256) void gemm_fused(const float* __restrict__ X,
                                                  const int* __restrict__ QW,
                                                  const float* __restrict__ scales,
                                                  const float* __restrict__ zeros,
                                                  const float* __restrict__ bias,
                                                  float* __restrict__ C) {
  __shared__ __align__(16) u16 As[BM * BK];
  __shared__ __align__(16) u16 Bs[BN * BK];
  const int tid = threadIdx.x;
  const int lane = tid & 63;
  const int wid = tid >> 6;
  const int bm = blockIdx.y, bn = blockIdx.x;
  const int row = tid >> 1;        // 0..127
  const int half = tid & 1;        // 32-wide k half
  const float* xr = X + (size_t)(bm * BM + row) * INF + half * 32;
  const int* qr = QW + (size_t)(bn * BN + row) * KB4 + half * 16;
  const float* srow = scales + (size_t)(bn * BN + row) * NG;
  const float* zrow = zeros + (size_t)(bn * BN + row) * NG;
  const int mwave = (wid >> 1) * 64;
  const int nwave = (wid & 1) * 64;
  f32x4 acc[4][4] = {};

  for (int kb = 0; kb < INF / BK; ++kb) {
    const int k0 = kb * BK;
    union { u16 t[32]; int4 v[4]; } ta, tb;
#pragma unroll
    for (int j = 0; j < 8; ++j) {
      const float4 f = *(const float4*)(xr + k0 + j * 4);
      ta.t[4 * j]     = f2bf(f.x);
      ta.t[4 * j + 1] = f2bf(f.y);
      ta.t[4 * j + 2] = f2bf(f.z);
      ta.t[4 * j + 3] = f2bf(f.w);
    }
    {
      const float s = srow[kb >> 1];
      const float zs = -zrow[kb >> 1] * s;
#pragma unroll
      for (int j = 0; j < 4; ++j) {
        const int4 q = *(const int4*)(qr + kb * 32 + j * 4);
        const int qq[4] = {q.x, q.y, q.z, q.w};
#pragma unroll
        for (int u = 0; u < 4; ++u) {
          tb.t[8 * j + 2 * u]     = f2bf(fmaf((float)(qq[u] & 15), s, zs));
          tb.t[8 * j + 2 * u + 1] = f2bf(fmaf((float)((qq[u] >> 4) & 15), s, zs));
        }
      }
    }
    __syncthreads();   // prior compute done before overwriting LDS
#pragma unroll
    for (int j = 0; j < 4; ++j) {
      *(int4*)&As[row * BK + half * 32 + j * 8] = ta.v[j];
      *(int4*)&Bs[row * BK + half * 32 + j * 8] = tb.v[j];
    }
    __syncthreads();
    MFMA_COMPUTE();
  }
  EPILOGUE();
}

// ---------------- launch ----------------

extern "C" void kernel_launch(void* const* d_in, const int* in_sizes, int n_in,
                              void* d_out, int out_size, void* d_ws, size_t ws_size,
                              hipStream_t stream) {
  const float* x = (const float*)d_in[0];
  const int* qw = (const int*)d_in[1];
  const float* scales = (const float*)d_in[2];
  const float* zeros = (const float*)d_in[3];
  const float* bias = (const float*)d_in[4];
  float* out = (float*)d_out;

  const size_t needW = (size_t)OUTF * INF * sizeof(u16);  // 90,177,536 B
  const size_t needX = (size_t)TOK * INF * sizeof(u16);   // 67,108,864 B
  const dim3 grid(OUTF / BN, TOK / BM);                   // 86 x 64

  if (ws_size >= needW + needX) {
    u16* Wb = (u16*)d_ws;
    u16* Xb = (u16*)((char*)d_ws + needW);
    dequant_w<<<(OUTF * KB4 / 4) / 256, 256, 0, stream>>>(qw, scales, zeros, Wb);
    cvt_x<<<(TOK * INF / 8) / 256, 256, 0, stream>>>(x, Xb);
    gemm_pre<<<grid, 256, 0, stream>>>(Xb, Wb, bias, out);
  } else {
    gemm_fused<<<grid, 256, 0, stream>>>(x, qw, scales, zeros, bias, out);
  }
}

// Round 2
// 1402.309 us; speedup vs baseline: 1.0133x; 1.0133x over previous
//
#include <hip/hip_runtime.h>
#include <stdint.h>

#define OUTF 11008
#define INF  4096
#define NG   32      // groups = INF/128
#define TOK  8192
#define KB4  2048    // int32 per qweight row = INF/2

#define BM 128
#define BN 128
#define BK 64

typedef unsigned short u16;
typedef __attribute__((ext_vector_type(8))) short bf16x8;
typedef __attribute__((ext_vector_type(4))) float f32x4;

// fp32 -> bf16 round-to-nearest-even (inputs finite)
__device__ inline u16 f2bf(float f) {
  union { float f; uint32_t u; } v; v.f = f;
  return (u16)((v.u + 0x7fff + ((v.u >> 16) & 1)) >> 16);
}

// async global->LDS, 16B per lane; lds dest must be wave-uniform base (+lane*16 implicit)
__device__ inline void async_copy16(const void* g, const void* l) {
  __builtin_amdgcn_global_load_lds(
      (__attribute__((address_space(1))) void*)(g),
      (__attribute__((address_space(3))) void*)(l), 16, 0, 0);
}

// ---------------- preprocessing kernels ----------------
// 32 B of packed input per thread.

__global__ void dequant_w(const int* __restrict__ QW, const float* __restrict__ scales,
                          const float* __restrict__ zeros, u16* __restrict__ Wb) {
  const int idx = blockIdx.x * 256 + threadIdx.x;   // one per 8 packed ints
  const int e = idx * 8;
  const int o = e >> 11;            // /KB4
  const int c = e & (KB4 - 1);      // multiple of 8 -> both int4s in same group
  const int g = c >> 6;
  const float s = scales[o * NG + g];
  const float z = zeros[o * NG + g];
  const float zs = -z * s;
#pragma unroll
  for (int h = 0; h < 2; ++h) {
    const int4 q = *(const int4*)(QW + (size_t)o * KB4 + c + h * 4);
    const int qq[4] = {q.x, q.y, q.z, q.w};
    union { u16 t[8]; int4 v; } u;
#pragma unroll
    for (int j = 0; j < 4; ++j) {
      u.t[2 * j]     = f2bf(fmaf((float)(qq[j] & 15), s, zs));
      u.t[2 * j + 1] = f2bf(fmaf((float)((qq[j] >> 4) & 15), s, zs));
    }
    *(int4*)(Wb + (size_t)o * INF + 2 * (c + h * 4)) = u.v;
  }
}

__global__ void cvt_x(const float* __restrict__ X, u16* __restrict__ Xb) {
  const size_t base = ((size_t)blockIdx.x * 256 + threadIdx.x) * 16;
#pragma unroll
  for (int h = 0; h < 2; ++h) {
    const float4 a = *(const float4*)(X + base + h * 8);
    const float4 b = *(const float4*)(X + base + h * 8 + 4);
    union { u16 t[8]; int4 v; } u;
    u.t[0] = f2bf(a.x); u.t[1] = f2bf(a.y); u.t[2] = f2bf(a.z); u.t[3] = f2bf(a.w);
    u.t[4] = f2bf(b.x); u.t[5] = f2bf(b.y); u.t[6] = f2bf(b.z); u.t[7] = f2bf(b.w);
    *(int4*)(Xb + base + h * 8) = u.v;
  }
}

// ---------------- shared GEMM compute/epilogue ----------------
// LDS layout XOR-swizzled: granule g (16B) of local row r stored at g ^ (r&7).
// A-frag: A[m=lane&15][k=(lane>>4)*8+j]; B-frag symmetric (B^T input).
// C/D: col=lane&15, row=(lane>>4)*4+reg.

#define MFMA_COMPUTE()                                                        \
  do {                                                                        \
    const int rr = lane & 15;                                                 \
    const int q4 = lane >> 4;                                                 \
    _Pragma("unroll") for (int ks = 0; ks < 2; ++ks) {                        \
      bf16x8 af[4], bfr[4];                                                   \
      const int kk = (((ks * 4 + q4) ^ (rr & 7)) * 8);  /* swizzled granule */\
      _Pragma("unroll") for (int i = 0; i < 4; ++i) {                         \
        af[i]  = *(const bf16x8*)&As[(mwave + i * 16 + rr) * BK + kk];        \
        bfr[i] = *(const bf16x8*)&Bs[(nwave + i * 16 + rr) * BK + kk];        \
      }                                                                       \
      _Pragma("unroll") for (int mi = 0; mi < 4; ++mi)                        \
        _Pragma("unroll") for (int ni = 0; ni < 4; ++ni)                      \
          acc[mi][ni] = __builtin_amdgcn_mfma_f32_16x16x32_bf16(              \
              af[mi], bfr[ni], acc[mi][ni], 0, 0, 0);                         \
    }                                                                         \
  } while (0)

#define EPILOGUE()                                                            \
  do {                                                                        \
    const int ncol = lane & 15;                                               \
    const int qrow = (lane >> 4) * 4;                                         \
    _Pragma("unroll") for (int mi = 0; mi < 4; ++mi)                          \
      _Pragma("unroll") for (int ni = 0; ni < 4; ++ni) {                      \
        const int gn = bn * BN + nwave + ni * 16 + ncol;                      \
        const float bv = bias[gn];                                            \
        _Pragma("unroll") for (int r = 0; r < 4; ++r) {                       \
          const int gm = bm * BM + mwave + mi * 16 + qrow + r;                \
          C[(size_t)gm * OUTF + gn] = acc[mi][ni][r] + bv;                    \
        }                                                                     \
      }                                                                       \
  } while (0)

// ---------------- main GEMM (preprocessed bf16 A,B in ws) ----------------

__global__ __launch_bounds__(256) void gemm_pre(const u16* __restrict__ A,
                                                const u16* __restrict__ B,
                                                const float* __restrict__ bias,
                                                float* __restrict__ C) {
  __shared__ __align__(16) u16 As[BM * BK];   // 16 KB, unpadded (global_load_lds)
  __shared__ __align__(16) u16 Bs[BN * BK];   // 16 KB
  const int tid = threadIdx.x;
  const int lane = tid & 63;
  const int wid = __builtin_amdgcn_readfirstlane(tid >> 6);
  const int bm = blockIdx.y, bn = blockIdx.x;
  const u16* Ab = A + (size_t)bm * BM * INF;
  const u16* Bb = B + (size_t)bn * BN * INF;
  const int sr = lane >> 3;                    // row within 8-row group
  const int sc = ((lane & 7) ^ sr) * 8;        // XOR-swizzled source granule
  const int mwave = (wid >> 1) * 64;
  const int nwave = (wid & 1) * 64;
  f32x4 acc[4][4] = {};

  for (int kb = 0; kb < INF / BK; ++kb) {
    const int k0 = kb * BK;
#pragma unroll
    for (int j = 0; j < 4; ++j) {
      const int rg = wid * 4 + j;          // 8-row group index, wave-uniform
      const int row = rg * 8 + sr;
      async_copy16(Ab + (size_t)row * INF + k0 + sc, (const char*)As + rg * 1024);
      async_copy16(Bb + (size_t)row * INF + k0 + sc, (const char*)Bs + rg * 1024);
    }
    __syncthreads();
    MFMA_COMPUTE();
    __syncthreads();
  }
  EPILOGUE();
}

// ---------------- fused fallback (no workspace requirement) ----------------

__global__ __launch_bounds__(256) void gemm_fused(const float* __restrict__ X,
                                                  const int* __restrict__ QW,
                                                  const float* __restrict__ scales,
                                                  const float* __restrict__ zeros,
                                                  const float* __restrict__ bias,
                                                  float* __restrict__ C) {
  __shared__ __align__(16) u16 As[BM * BK];
  __shared__ __align__(16) u16 Bs[BN * BK];
  const int tid = threadIdx.x;
  const int lane = tid & 63;
  const int wid = tid >> 6;
  const int bm = blockIdx.y, bn = blockIdx.x;
  const int row = tid >> 1;        // 0..127
  const int half = tid & 1;        // 32-wide k half
  const float* xr = X + (size_t)(bm * BM + row) * INF + half * 32;
  const int* qr = QW + (size_t)(bn * BN + row) * KB4 + half * 16;
  const float* srow = scales + (size_t)(bn * BN + row) * NG;
  const float* zrow = zeros + (size_t)(bn * BN + row) * NG;
  const int mwave = (wid >> 1) * 64;
  const int nwave = (wid & 1) * 64;
  f32x4 acc[4][4] = {};

  for (int kb = 0; kb < INF / BK; ++kb) {
    const int k0 = kb * BK;
    union { u16 t[32]; int4 v[4]; } ta, tb;
#pragma unroll
    for (int j = 0; j < 8; ++j) {
      const float4 f = *(const float4*)(xr + k0 + j * 4);
      ta.t[4 * j]     = f2bf(f.x);
      ta.t[4 * j + 1] = f2bf(f.y);
      ta.t[4 * j + 2] = f2bf(f.z);
      ta.t[4 * j + 3] = f2bf(f.w);
    }
    {
      const float s = srow[kb >> 1];
      const float zs = -zrow[kb >> 1] * s;
#pragma unroll
      for (int j = 0; j < 4; ++j) {
        const int4 q = *(const int4*)(qr + kb * 32 + j * 4);
        const int qq[4] = {q.x, q.y, q.z, q.w};
#pragma unroll
        for (int u = 0; u < 4; ++u) {
          tb.t[8 * j + 2 * u]     = f2bf(fmaf((float)(qq[u] & 15), s, zs));
          tb.t[8 * j + 2 * u + 1] = f2bf(fmaf((float)((qq[u] >> 4) & 15), s, zs));
        }
      }
    }
    __syncthreads();   // prior compute done before overwriting LDS
#pragma unroll
    for (int j = 0; j < 4; ++j) {
      *(int4*)&As[row * BK + (((half * 4 + j) ^ (row & 7)) * 8)] = ta.v[j];
      *(int4*)&Bs[row * BK + (((half * 4 + j) ^ (row & 7)) * 8)] = tb.v[j];
    }
    __syncthreads();
    MFMA_COMPUTE();
  }
  EPILOGUE();
}

// ---------------- launch ----------------

extern "C" void kernel_launch(void* const* d_in, const int* in_sizes, int n_in,
                              void* d_out, int out_size, void* d_ws, size_t ws_size,
                              hipStream_t stream) {
  const float* x = (const float*)d_in[0];
  const int* qw = (const int*)d_in[1];
  const float* scales = (const float*)d_in[2];
  const float* zeros = (const float*)d_in[3];
  const float* bias = (const float*)d_in[4];
  float* out = (float*)d_out;

  const size_t needW = (size_t)OUTF * INF * sizeof(u16);  // 90,177,536 B
  const size_t needX = (size_t)TOK * INF * sizeof(u16);   // 67,108,864 B
  const dim3 grid(OUTF / BN, TOK / BM);                   // 86 x 64

  if (ws_size >= needW + needX) {
    u16* Wb = (u16*)d_ws;
    u16* Xb = (u16*)((char*)d_ws + needW);
    dequant_w<<<(OUTF * KB4 / 8) / 256, 256, 0, stream>>>(qw, scales, zeros, Wb);
    cvt_x<<<(TOK * INF / 16) / 256, 256, 0, stream>>>(x, Xb);
    gemm_pre<<<grid, 256, 0, stream>>>(Xb, Wb, bias, out);
  } else {
    gemm_fused<<<grid, 256, 0, stream>>>(x, qw, scales, zeros, bias, out);
  }
}